// Round 10
// baseline (50.333 us; speedup 1.0000x reference)
//
#include <hip/hip_runtime.h>

namespace {
constexpr int B = 4, C = 64, H = 128, W = 128, O = 64, KK = 9;
constexpr int PREPT = 256;
constexpr int WF_ELEMS = KK * 2 * 4 * 64 * 8;                   // 36864
constexpr size_t XT_BYTES = (size_t)B * H * W * C * 2;          // 16,777,216 (f16)
constexpr size_t WF_BYTES = (size_t)WF_ELEMS * 2;               // 73,728 (8KB per tap)
constexpr size_t WS_NEED  = XT_BYTES + WF_BYTES;
}

typedef float    f32x4 __attribute__((ext_vector_type(4)));
typedef _Float16 f16x2 __attribute__((ext_vector_type(2)));
typedef _Float16 f16x8 __attribute__((ext_vector_type(8)));

__device__ __forceinline__ unsigned hpack2(float a, float b) {  // 2x f32 -> packed f16
  f16x2 v; v[0] = (_Float16)a; v[1] = (_Float16)b;
  return __builtin_bit_cast(unsigned, v);
}
__device__ __forceinline__ void gload16(const void* g, void* l) {
  __builtin_amdgcn_global_load_lds(
      (const __attribute__((address_space(1))) unsigned*)g,
      (__attribute__((address_space(3))) unsigned*)l, 16, 0, 0);
}

// ---------- prep: x[b][c][h][w] f32 -> x_t[b][h][w][c] f16,  + weight->f16 frag ----------
__global__ __launch_bounds__(PREPT)
void prep_fused(const float* __restrict__ x, const float* __restrict__ wgt,
                unsigned* __restrict__ xt_u32, unsigned short* __restrict__ wf) {
  __shared__ float st[64][65];
  const int t = threadIdx.x;

  // weight -> f16 A-fragment order: o = mt*16 + (lane&15), c = ks*32 + (lane>>4)*8 + e
  const int gid = blockIdx.x * PREPT + t;
  if (gid < WF_ELEMS) {
    const int e = gid & 7, lane = (gid >> 3) & 63, mt = (gid >> 9) & 3;
    const int ks = (gid >> 11) & 1, tap = gid >> 12;
    const int o = mt * 16 + (lane & 15);
    const int c = ks * 32 + ((lane >> 4) << 3) + e;
    const _Float16 hv = (_Float16)wgt[(size_t)o * (C * KK) + c * KK + tap];
    wf[gid] = __builtin_bit_cast(unsigned short, hv);
  }

  const int half = blockIdx.x & 1, h = (blockIdx.x >> 1) & 127, b = blockIdx.x >> 8;
  const int w0 = half * 64;
#pragma unroll
  for (int it = 0; it < 16; ++it) {
    const int w = t & 63, c = it * 4 + (t >> 6);
    st[w][c] = x[((size_t)(b * C + c) * H + h) * W + w0 + w];
  }
  __syncthreads();
#pragma unroll
  for (int it = 0; it < 8; ++it) {
    const int idx = it * PREPT + t;
    const int w = idx >> 5, c2 = (idx & 31) * 2;
    xt_u32[(size_t)(((b * H + h) * W) + w0 + w) * 32 + (c2 >> 1)] = hpack2(st[w][c2], st[w][c2 + 1]);
  }
}

// ---------- main: B-fragment built directly in registers (no s_m round-trip) ----------
__global__ __launch_bounds__(256) __attribute__((amdgpu_waves_per_eu(4, 4)))
void deform_mfma(const float* __restrict__ offs, const char* __restrict__ xt,
                 const char* __restrict__ wfg, float* __restrict__ out) {
  __shared__ unsigned short s_wf[2][4096];     // 16 KB: dbuf of one tap's A-fragments
  __shared__ unsigned s_pw[4][KK][16][2];      // 4.5 KB: f16x2 pairs (w00,w01),(w10,w11)
  __shared__ unsigned s_pa[4][KK][16][4];      // 9 KB:  4 corner byte-addrs

  const int t = threadIdx.x, l = t & 63, wid = t >> 6;
  const int nid  = (blockIdx.x & 7) * 128 + (blockIdx.x >> 3);   // bijective XCD swizzle
  const int half = nid & 1, h = (nid >> 1) & 127, b = nid >> 8;
  const int wbase = half * 64 + wid * 16;

  // --- sampling params: wave's 16 px x 9 taps ---
#pragma unroll
  for (int it = 0; it < 3; ++it) {
    const int item = it * 64 + l;
    if (item < KK * 16) {
      const int tap = item >> 4, pix = item & 15;
      const int ki = tap / 3, kj = tap - ki * 3;
      const int w = wbase + pix;
      const float* ob = offs + ((size_t)b * (2 * KK) + 2 * tap) * (H * W) + h * W + w;
      const float oi = ob[0], oj = ob[H * W];
      const float ci = oi + (float)(h + ki - 1);
      const float cj = oj + (float)(w + kj - 1);
      const float fli = floorf(ci), flj = floorf(cj);
      const int i0 = (int)fli, j0 = (int)flj, i1 = i0 + 1, j1 = j0 + 1;
      const float fi = ci - fli, fj = cj - flj, gi = 1.f - fi, gj = 1.f - fj;
      const bool bi0 = (unsigned)i0 < (unsigned)H, bi1 = (unsigned)i1 < (unsigned)H;
      const bool bj0 = (unsigned)j0 < (unsigned)W, bj1 = (unsigned)j1 < (unsigned)W;
      const int ic0 = min(max(i0, 0), H - 1), ic1 = min(max(i1, 0), H - 1);
      const int jc0 = min(max(j0, 0), W - 1), jc1 = min(max(j1, 0), W - 1);
      const float w00 = gi * gj * (float)(bi0 && bj0);
      const float w01 = gi * fj * (float)(bi0 && bj1);
      const float w10 = fi * gj * (float)(bi1 && bj0);
      const float w11 = fi * fj * (float)(bi1 && bj1);
      s_pw[wid][tap][pix][0] = hpack2(w00, w01);
      s_pw[wid][tap][pix][1] = hpack2(w10, w11);
      s_pa[wid][tap][pix][0] = (unsigned)(((b * H + ic0) * W + jc0) << 7);
      s_pa[wid][tap][pix][1] = (unsigned)(((b * H + ic0) * W + jc1) << 7);
      s_pa[wid][tap][pix][2] = (unsigned)(((b * H + ic1) * W + jc0) << 7);
      s_pa[wid][tap][pix][3] = (unsigned)(((b * H + ic1) * W + jc1) << 7);
    }
  }

  // B-fragment lane map: px = l&15 (n-dim), 16B chunk (l>>4) of ks-half (64B) of px row
  const int px   = l & 15;
  const int cb16 = (l >> 4) << 4;

  f32x4 acc[4];
#pragma unroll
  for (int mt = 0; mt < 4; ++mt) acc[mt] = (f32x4)0.f;

  // ring of 2 taps: G[c*2+ks], 8 x uint4 per tap (32 VGPR each)
  uint4 gA[8], gB[8];
#define ISSUE(TAPX, G) do {                                                    \
    const uint4 ad = *(const uint4*)&s_pa[wid][(TAPX)][px][0];                 \
    G[0] = *(const uint4*)(xt + ad.x + cb16);                                  \
    G[1] = *(const uint4*)(xt + ad.x + cb16 + 64);                             \
    G[2] = *(const uint4*)(xt + ad.y + cb16);                                  \
    G[3] = *(const uint4*)(xt + ad.y + cb16 + 64);                             \
    G[4] = *(const uint4*)(xt + ad.z + cb16);                                  \
    G[5] = *(const uint4*)(xt + ad.z + cb16 + 64);                             \
    G[6] = *(const uint4*)(xt + ad.w + cb16);                                  \
    G[7] = *(const uint4*)(xt + ad.w + cb16 + 64);                             \
  } while (0)

  // packed-f16 lerp of one ks-half: corners G[0/2/4/6]+ks -> one f16x8 B-fragment
#define LERPW(G, KS, R) do {                                                   \
    uint4 r_;                                                                  \
    r_.x = __builtin_bit_cast(unsigned, (f16x2)(                               \
      __builtin_bit_cast(f16x2, G[0 + KS].x) * W00 + __builtin_bit_cast(f16x2, G[2 + KS].x) * W01 + \
      __builtin_bit_cast(f16x2, G[4 + KS].x) * W10 + __builtin_bit_cast(f16x2, G[6 + KS].x) * W11)); \
    r_.y = __builtin_bit_cast(unsigned, (f16x2)(                               \
      __builtin_bit_cast(f16x2, G[0 + KS].y) * W00 + __builtin_bit_cast(f16x2, G[2 + KS].y) * W01 + \
      __builtin_bit_cast(f16x2, G[4 + KS].y) * W10 + __builtin_bit_cast(f16x2, G[6 + KS].y) * W11)); \
    r_.z = __builtin_bit_cast(unsigned, (f16x2)(                               \
      __builtin_bit_cast(f16x2, G[0 + KS].z) * W00 + __builtin_bit_cast(f16x2, G[2 + KS].z) * W01 + \
      __builtin_bit_cast(f16x2, G[4 + KS].z) * W10 + __builtin_bit_cast(f16x2, G[6 + KS].z) * W11)); \
    r_.w = __builtin_bit_cast(unsigned, (f16x2)(                               \
      __builtin_bit_cast(f16x2, G[0 + KS].w) * W00 + __builtin_bit_cast(f16x2, G[2 + KS].w) * W01 + \
      __builtin_bit_cast(f16x2, G[4 + KS].w) * W10 + __builtin_bit_cast(f16x2, G[6 + KS].w) * W11)); \
    R = __builtin_bit_cast(f16x8, r_);                                         \
  } while (0)

  // prologue: stage tap 0's weights into buf 0, prefetch tap 0's gathers
  {
    const char* src = wfg + (size_t)t * 16;
    char* dst = (char*)s_wf + t * 16;
    gload16(src, dst);
    gload16(src + 4096, dst + 4096);
  }
  ISSUE(0, gA);

#pragma unroll
  for (int tap = 0; tap < KK; ++tap) {
    uint4* gc = (tap & 1) ? gB : gA;   // static under full unroll (rule #20)
    uint4* gn = (tap & 1) ? gA : gB;

    __syncthreads();   // s_wf buf[tap&1] ready; prev-buf A-reads drained

    if (tap + 1 < KK) {                // stage next tap's weights + gathers
      const char* src = wfg + (size_t)(tap + 1) * 8192 + t * 16;
      char* dst = (char*)s_wf + ((tap + 1) & 1) * 8192 + t * 16;
      gload16(src, dst);
      gload16(src + 4096, dst + 4096);
      ISSUE(tap + 1, gn);
      __builtin_amdgcn_sched_barrier(0);   // pin: no sinking of prefetches
    }

    // --- lerp current tap -> B-fragments in registers ---
    const uint2 pk = *(const uint2*)&s_pw[wid][tap][px][0];
    const f16x2 pa_ = __builtin_bit_cast(f16x2, pk.x);
    const f16x2 pb_ = __builtin_bit_cast(f16x2, pk.y);
    const f16x2 W00 = {pa_[0], pa_[0]}, W01 = {pa_[1], pa_[1]};
    const f16x2 W10 = {pb_[0], pb_[0]}, W11 = {pb_[1], pb_[1]};
    f16x8 b0, b1;
    LERPW(gc, 0, b0);
    LERPW(gc, 1, b1);

    // --- A from LDS wf buffer, 8 MFMA ---
    const char* wl = (const char*)s_wf + (tap & 1) * 8192;
#pragma unroll
    for (int mt = 0; mt < 4; ++mt) {
      const f16x8 a0 = *(const f16x8*)(wl + mt * 1024 + l * 16);
      acc[mt] = __builtin_amdgcn_mfma_f32_16x16x32_f16(a0, b0, acc[mt], 0, 0, 0);
    }
#pragma unroll
    for (int mt = 0; mt < 4; ++mt) {
      const f16x8 a1 = *(const f16x8*)(wl + 4096 + mt * 1024 + l * 16);
      acc[mt] = __builtin_amdgcn_mfma_f32_16x16x32_f16(a1, b1, acc[mt], 0, 0, 0);
    }
  }
#undef ISSUE
#undef LERPW

  // --- epilogue: coalesced stores (D: col=lane&15 -> pixel, row=(lane>>4)*4+j -> o) ---
#pragma unroll
  for (int mt = 0; mt < 4; ++mt)
#pragma unroll
    for (int j = 0; j < 4; ++j) {
      const int o = mt * 16 + ((l >> 4) << 2) + j;
      out[((size_t)(b * O + o) * H + h) * W + wbase + px] = acc[mt][j];
    }
}

// ---------- fallback (round-1 kernel, used only if ws too small) ----------
namespace fb {
constexpr int WT = 32, CH = 16, NCHUNK = 4, KC = 144, WPAD = 68;
}
__global__ __launch_bounds__(PREPT, 2)
void deform_conv_fused(const float* __restrict__ x, const float* __restrict__ offs,
                       const float* __restrict__ wgt, float* __restrict__ out) {
  using namespace fb;
  __shared__ int   s_i0[KK][WT];
  __shared__ int   s_j0[KK][WT];
  __shared__ float s_fi[KK][WT];
  __shared__ float s_fj[KK][WT];
  __shared__ float s_w[KC][WPAD];
  __shared__ float s_m[KC][WT + 1];
  const int t = threadIdx.x;
  const int nwt = W / WT;
  const int wt = blockIdx.x % nwt, h = (blockIdx.x / nwt) % H, b = blockIdx.x / (nwt * H);
  const int w0 = wt * WT;
  for (int idx = t; idx < KK * WT; idx += PREPT) {
    const int k = idx / WT, p = idx % WT, w = w0 + p;
    const float oi = offs[(((size_t)b * (2 * KK) + 2 * k) * H + h) * W + w];
    const float oj = offs[(((size_t)b * (2 * KK) + 2 * k + 1) * H + h) * W + w];
    const float ci = oi + (float)(h + (k / 3) - 1), cj = oj + (float)(w + (k % 3) - 1);
    const float fli = floorf(ci), flj = floorf(cj);
    s_i0[k][p] = (int)fli; s_j0[k][p] = (int)flj;
    s_fi[k][p] = ci - fli; s_fj[k][p] = cj - flj;
  }
  float acc[8];
#pragma unroll
  for (int i = 0; i < 8; ++i) acc[i] = 0.f;
  const int p = t & (WT - 1), ob = (t >> 5) * 8;
  for (int cc = 0; cc < NCHUNK; ++cc) {
    const int c0 = cc * CH;
    __syncthreads();
    for (int idx = t; idx < O * KC; idx += PREPT)
      s_w[idx % KC][idx / KC] = wgt[(size_t)(idx / KC) * (C * KK) + (size_t)c0 * KK + idx % KC];
    for (int idx = t; idx < CH * KK * WT; idx += PREPT) {
      const int pp = idx & (WT - 1), rest = idx >> 5, k = rest % KK, cl = rest / KK;
      const int i0 = s_i0[k][pp], j0 = s_j0[k][pp], i1 = i0 + 1, j1 = j0 + 1;
      const float fi = s_fi[k][pp], fj = s_fj[k][pp];
      const float* xb = x + (size_t)(b * C + c0 + cl) * H * W;
      const float v00 = ((unsigned)i0 < (unsigned)H && (unsigned)j0 < (unsigned)W) ? xb[i0 * W + j0] : 0.f;
      const float v01 = ((unsigned)i0 < (unsigned)H && (unsigned)j1 < (unsigned)W) ? xb[i0 * W + j1] : 0.f;
      const float v10 = ((unsigned)i1 < (unsigned)H && (unsigned)j0 < (unsigned)W) ? xb[i1 * W + j0] : 0.f;
      const float v11 = ((unsigned)i1 < (unsigned)H && (unsigned)j1 < (unsigned)W) ? xb[i1 * W + j1] : 0.f;
      const float top = v00 + fj * (v01 - v00), bot = v10 + fj * (v11 - v10);
      s_m[cl * KK + k][pp] = top + fi * (bot - top);
    }
    __syncthreads();
#pragma unroll 4
    for (int k = 0; k < KC; ++k) {
      const float a = s_m[k][p];
      const float4 wv0 = *reinterpret_cast<const float4*>(&s_w[k][ob]);
      const float4 wv1 = *reinterpret_cast<const float4*>(&s_w[k][ob + 4]);
      acc[0] += a * wv0.x; acc[1] += a * wv0.y; acc[2] += a * wv0.z; acc[3] += a * wv0.w;
      acc[4] += a * wv1.x; acc[5] += a * wv1.y; acc[6] += a * wv1.z; acc[7] += a * wv1.w;
    }
  }
#pragma unroll
  for (int i = 0; i < 8; ++i)
    out[(((size_t)b * O + ob + i) * H + h) * W + w0 + p] = acc[i];
}

extern "C" void kernel_launch(void* const* d_in, const int* in_sizes, int n_in,
                              void* d_out, int out_size, void* d_ws, size_t ws_size,
                              hipStream_t stream) {
  const float* x    = (const float*)d_in[0];
  const float* offs = (const float*)d_in[1];
  const float* wgt  = (const float*)d_in[2];
  float* out = (float*)d_out;

  if (ws_size < WS_NEED) {   // fallback: round-1 kernel
    deform_conv_fused<<<B * H * (W / 32), PREPT, 0, stream>>>(x, offs, wgt, out);
    return;
  }
  char* xt = (char*)d_ws;
  unsigned short* wf = (unsigned short*)(xt + XT_BYTES);

  prep_fused<<<B * H * 2, PREPT, 0, stream>>>(x, wgt, (unsigned*)xt, wf);
  deform_mfma<<<B * H * 2, 256, 0, stream>>>(offs, xt, (const char*)wf, out);
}

// Round 12
// 50.168 us; speedup vs baseline: 1.0033x; 1.0033x over previous
//
#include <hip/hip_runtime.h>

namespace {
constexpr int B = 4, C = 64, H = 128, W = 128, O = 64, KK = 9;
constexpr int PREPT = 256;
constexpr int WF_ELEMS = KK * 2 * 4 * 64 * 8;                   // 36864
constexpr size_t XT_BYTES = (size_t)B * H * W * C * 2;          // 16,777,216 (f16)
constexpr size_t WF_BYTES = (size_t)WF_ELEMS * 2;               // 73,728 (8KB per tap)
constexpr size_t WS_NEED  = XT_BYTES + WF_BYTES;
}

typedef float    f32x4 __attribute__((ext_vector_type(4)));
typedef _Float16 f16x2 __attribute__((ext_vector_type(2)));
typedef _Float16 f16x8 __attribute__((ext_vector_type(8)));

__device__ __forceinline__ unsigned hpack2(float a, float b) {  // 2x f32 -> packed f16
  f16x2 v; v[0] = (_Float16)a; v[1] = (_Float16)b;
  return __builtin_bit_cast(unsigned, v);
}
__device__ __forceinline__ void gload16(const void* g, void* l) {
  __builtin_amdgcn_global_load_lds(
      (const __attribute__((address_space(1))) unsigned*)g,
      (__attribute__((address_space(3))) unsigned*)l, 16, 0, 0);
}

// ---------- prep: x[b][c][h][w] f32 -> x_t[b][h][w][c] f16,  + weight->f16 frag ----------
__global__ __launch_bounds__(PREPT)
void prep_fused(const float* __restrict__ x, const float* __restrict__ wgt,
                unsigned* __restrict__ xt_u32, unsigned short* __restrict__ wf) {
  __shared__ float st[64][65];
  const int t = threadIdx.x;

  // weight -> f16 A-fragment order: o = mt*16 + (lane&15), c = ks*32 + (lane>>4)*8 + e
  const int gid = blockIdx.x * PREPT + t;
  if (gid < WF_ELEMS) {
    const int e = gid & 7, lane = (gid >> 3) & 63, mt = (gid >> 9) & 3;
    const int ks = (gid >> 11) & 1, tap = gid >> 12;
    const int o = mt * 16 + (lane & 15);
    const int c = ks * 32 + ((lane >> 4) << 3) + e;
    const _Float16 hv = (_Float16)wgt[(size_t)o * (C * KK) + c * KK + tap];
    wf[gid] = __builtin_bit_cast(unsigned short, hv);
  }

  const int half = blockIdx.x & 1, h = (blockIdx.x >> 1) & 127, b = blockIdx.x >> 8;
  const int w0 = half * 64;
#pragma unroll
  for (int it = 0; it < 16; ++it) {
    const int w = t & 63, c = it * 4 + (t >> 6);
    st[w][c] = x[((size_t)(b * C + c) * H + h) * W + w0 + w];
  }
  __syncthreads();
#pragma unroll
  for (int it = 0; it < 8; ++it) {
    const int idx = it * PREPT + t;
    const int w = idx >> 5, c2 = (idx & 31) * 2;
    xt_u32[(size_t)(((b * H + h) * W) + w0 + w) * 32 + (c2 >> 1)] = hpack2(st[w][c2], st[w][c2 + 1]);
  }
}

// ---------- main: direct-B lane map, 32-VGPR half-stage ring, no s_m ----------
__global__ __launch_bounds__(256) __attribute__((amdgpu_waves_per_eu(4)))
void deform_mfma(const float* __restrict__ offs, const char* __restrict__ xt,
                 const char* __restrict__ wfg, float* __restrict__ out) {
  __shared__ unsigned short s_wf[2][4096];     // 16 KB: dbuf of one tap's A-fragments
  __shared__ unsigned s_pw[4][KK][16][2];      // 4.5 KB: f16x2 pairs (w00,w01),(w10,w11)
  __shared__ unsigned s_pa[4][KK][16][4];      // 9 KB:  4 corner byte-addrs

  const int t = threadIdx.x, l = t & 63, wid = t >> 6;
  const int nid  = (blockIdx.x & 7) * 128 + (blockIdx.x >> 3);   // bijective XCD swizzle
  const int half = nid & 1, h = (nid >> 1) & 127, b = nid >> 8;
  const int wbase = half * 64 + wid * 16;

  // --- sampling params: wave's 16 px x 9 taps ---
#pragma unroll
  for (int it = 0; it < 3; ++it) {
    const int item = it * 64 + l;
    if (item < KK * 16) {
      const int tap = item >> 4, pix = item & 15;
      const int ki = tap / 3, kj = tap - ki * 3;
      const int w = wbase + pix;
      const float* ob = offs + ((size_t)b * (2 * KK) + 2 * tap) * (H * W) + h * W + w;
      const float oi = ob[0], oj = ob[H * W];
      const float ci = oi + (float)(h + ki - 1);
      const float cj = oj + (float)(w + kj - 1);
      const float fli = floorf(ci), flj = floorf(cj);
      const int i0 = (int)fli, j0 = (int)flj, i1 = i0 + 1, j1 = j0 + 1;
      const float fi = ci - fli, fj = cj - flj, gi = 1.f - fi, gj = 1.f - fj;
      const bool bi0 = (unsigned)i0 < (unsigned)H, bi1 = (unsigned)i1 < (unsigned)H;
      const bool bj0 = (unsigned)j0 < (unsigned)W, bj1 = (unsigned)j1 < (unsigned)W;
      const int ic0 = min(max(i0, 0), H - 1), ic1 = min(max(i1, 0), H - 1);
      const int jc0 = min(max(j0, 0), W - 1), jc1 = min(max(j1, 0), W - 1);
      const float w00 = gi * gj * (float)(bi0 && bj0);
      const float w01 = gi * fj * (float)(bi0 && bj1);
      const float w10 = fi * gj * (float)(bi1 && bj0);
      const float w11 = fi * fj * (float)(bi1 && bj1);
      s_pw[wid][tap][pix][0] = hpack2(w00, w01);
      s_pw[wid][tap][pix][1] = hpack2(w10, w11);
      s_pa[wid][tap][pix][0] = (unsigned)(((b * H + ic0) * W + jc0) << 7);
      s_pa[wid][tap][pix][1] = (unsigned)(((b * H + ic0) * W + jc1) << 7);
      s_pa[wid][tap][pix][2] = (unsigned)(((b * H + ic1) * W + jc0) << 7);
      s_pa[wid][tap][pix][3] = (unsigned)(((b * H + ic1) * W + jc1) << 7);
    }
  }

  // B-fragment lane map: px = l&15 (n-dim), chunk (l>>4)*16B of each ks-half
  const int px   = l & 15;
  const int cb16 = (l >> 4) << 4;

  f32x4 acc[4];
#pragma unroll
  for (int mt = 0; mt < 4; ++mt) acc[mt] = (f32x4)0.f;

  // half-stage ring: g0 = ks0 halves of 4 corners, g1 = ks1 halves (16 VGPR each)
  uint4 g0[4], g1[4];
#define ISSUE0(AD) do {                                                        \
    g0[0] = *(const uint4*)(xt + (AD).x + cb16);                               \
    g0[1] = *(const uint4*)(xt + (AD).y + cb16);                               \
    g0[2] = *(const uint4*)(xt + (AD).z + cb16);                               \
    g0[3] = *(const uint4*)(xt + (AD).w + cb16);                               \
  } while (0)
#define ISSUE1(AD) do {                                                        \
    g1[0] = *(const uint4*)(xt + (AD).x + cb16 + 64);                          \
    g1[1] = *(const uint4*)(xt + (AD).y + cb16 + 64);                          \
    g1[2] = *(const uint4*)(xt + (AD).z + cb16 + 64);                          \
    g1[3] = *(const uint4*)(xt + (AD).w + cb16 + 64);                          \
  } while (0)

  // packed-f16 lerp of one ks-half ring stage -> one f16x8 B-fragment
#define LERPW(G, R) do {                                                       \
    uint4 r_;                                                                  \
    r_.x = __builtin_bit_cast(unsigned, (f16x2)(                               \
      __builtin_bit_cast(f16x2, G[0].x) * W00 + __builtin_bit_cast(f16x2, G[1].x) * W01 + \
      __builtin_bit_cast(f16x2, G[2].x) * W10 + __builtin_bit_cast(f16x2, G[3].x) * W11)); \
    r_.y = __builtin_bit_cast(unsigned, (f16x2)(                               \
      __builtin_bit_cast(f16x2, G[0].y) * W00 + __builtin_bit_cast(f16x2, G[1].y) * W01 + \
      __builtin_bit_cast(f16x2, G[2].y) * W10 + __builtin_bit_cast(f16x2, G[3].y) * W11)); \
    r_.z = __builtin_bit_cast(unsigned, (f16x2)(                               \
      __builtin_bit_cast(f16x2, G[0].z) * W00 + __builtin_bit_cast(f16x2, G[1].z) * W01 + \
      __builtin_bit_cast(f16x2, G[2].z) * W10 + __builtin_bit_cast(f16x2, G[3].z) * W11)); \
    r_.w = __builtin_bit_cast(unsigned, (f16x2)(                               \
      __builtin_bit_cast(f16x2, G[0].w) * W00 + __builtin_bit_cast(f16x2, G[1].w) * W01 + \
      __builtin_bit_cast(f16x2, G[2].w) * W10 + __builtin_bit_cast(f16x2, G[3].w) * W11)); \
    R = __builtin_bit_cast(f16x8, r_);                                         \
  } while (0)

  // prologue: stage tap 0's weights into buf 0, prefetch tap 0's gathers
  {
    const char* src = wfg + (size_t)t * 16;
    char* dst = (char*)s_wf + t * 16;
    gload16(src, dst);
    gload16(src + 4096, dst + 4096);
  }
  {
    const uint4 ad0 = *(const uint4*)&s_pa[wid][0][px][0];
    ISSUE0(ad0);
    ISSUE1(ad0);
  }

#pragma unroll
  for (int tap = 0; tap < KK; ++tap) {
    __syncthreads();   // s_wf buf[tap&1] ready; prev-buf A-reads drained

    if (tap + 1 < KK) {                // stage next tap's weights
      const char* src = wfg + (size_t)(tap + 1) * 8192 + t * 16;
      char* dst = (char*)s_wf + ((tap + 1) & 1) * 8192 + t * 16;
      gload16(src, dst);
      gload16(src + 4096, dst + 4096);
    }

    const uint2 pk = *(const uint2*)&s_pw[wid][tap][px][0];
    const f16x2 pa_ = __builtin_bit_cast(f16x2, pk.x);
    const f16x2 pb_ = __builtin_bit_cast(f16x2, pk.y);
    const f16x2 W00 = {pa_[0], pa_[0]}, W01 = {pa_[1], pa_[1]};
    const f16x2 W10 = {pb_[0], pb_[0]}, W11 = {pb_[1], pb_[1]};

    uint4 adn;
    if (tap + 1 < KK) adn = *(const uint4*)&s_pa[wid][tap + 1][px][0];

    const char* wl = (const char*)s_wf + (tap & 1) * 8192;

    // --- half-stage 0: lerp ks0, refill g0 for next tap, 4 MFMA ---
    f16x8 b0;
    LERPW(g0, b0);
    if (tap + 1 < KK) { ISSUE0(adn); __builtin_amdgcn_sched_barrier(0); }
#pragma unroll
    for (int mt = 0; mt < 4; ++mt) {
      const f16x8 a0 = *(const f16x8*)(wl + mt * 1024 + l * 16);
      acc[mt] = __builtin_amdgcn_mfma_f32_16x16x32_f16(a0, b0, acc[mt], 0, 0, 0);
    }

    // --- half-stage 1: lerp ks1, refill g1 for next tap, 4 MFMA ---
    f16x8 b1;
    LERPW(g1, b1);
    if (tap + 1 < KK) { ISSUE1(adn); __builtin_amdgcn_sched_barrier(0); }
#pragma unroll
    for (int mt = 0; mt < 4; ++mt) {
      const f16x8 a1 = *(const f16x8*)(wl + 4096 + mt * 1024 + l * 16);
      acc[mt] = __builtin_amdgcn_mfma_f32_16x16x32_f16(a1, b1, acc[mt], 0, 0, 0);
    }

    // keep-alive: pin ring loads (scalar components — vector operands are not
    // valid "v" asm inputs). Referencing .x forces each dwordx4 to have
    // executed before this point; prevents sinking past __syncthreads.
    if (tap + 1 < KK) {
      asm volatile("" :: "v"(g0[0].x), "v"(g0[1].x), "v"(g0[2].x), "v"(g0[3].x),
                         "v"(g1[0].x), "v"(g1[1].x), "v"(g1[2].x), "v"(g1[3].x));
    }
  }
#undef ISSUE0
#undef ISSUE1
#undef LERPW

  // --- epilogue: coalesced stores (D: col=lane&15 -> pixel, row=(lane>>4)*4+j -> o) ---
#pragma unroll
  for (int mt = 0; mt < 4; ++mt)
#pragma unroll
    for (int j = 0; j < 4; ++j) {
      const int o = mt * 16 + ((l >> 4) << 2) + j;
      out[((size_t)(b * O + o) * H + h) * W + wbase + px] = acc[mt][j];
    }
}

// ---------- fallback (round-1 kernel, used only if ws too small) ----------
namespace fb {
constexpr int WT = 32, CH = 16, NCHUNK = 4, KC = 144, WPAD = 68;
}
__global__ __launch_bounds__(PREPT, 2)
void deform_conv_fused(const float* __restrict__ x, const float* __restrict__ offs,
                       const float* __restrict__ wgt, float* __restrict__ out) {
  using namespace fb;
  __shared__ int   s_i0[KK][WT];
  __shared__ int   s_j0[KK][WT];
  __shared__ float s_fi[KK][WT];
  __shared__ float s_fj[KK][WT];
  __shared__ float s_w[KC][WPAD];
  __shared__ float s_m[KC][WT + 1];
  const int t = threadIdx.x;
  const int nwt = W / WT;
  const int wt = blockIdx.x % nwt, h = (blockIdx.x / nwt) % H, b = blockIdx.x / (nwt * H);
  const int w0 = wt * WT;
  for (int idx = t; idx < KK * WT; idx += PREPT) {
    const int k = idx / WT, p = idx % WT, w = w0 + p;
    const float oi = offs[(((size_t)b * (2 * KK) + 2 * k) * H + h) * W + w];
    const float oj = offs[(((size_t)b * (2 * KK) + 2 * k + 1) * H + h) * W + w];
    const float ci = oi + (float)(h + (k / 3) - 1), cj = oj + (float)(w + (k % 3) - 1);
    const float fli = floorf(ci), flj = floorf(cj);
    s_i0[k][p] = (int)fli; s_j0[k][p] = (int)flj;
    s_fi[k][p] = ci - fli; s_fj[k][p] = cj - flj;
  }
  float acc[8];
#pragma unroll
  for (int i = 0; i < 8; ++i) acc[i] = 0.f;
  const int p = t & (WT - 1), ob = (t >> 5) * 8;
  for (int cc = 0; cc < NCHUNK; ++cc) {
    const int c0 = cc * CH;
    __syncthreads();
    for (int idx = t; idx < O * KC; idx += PREPT)
      s_w[idx % KC][idx / KC] = wgt[(size_t)(idx / KC) * (C * KK) + (size_t)c0 * KK + idx % KC];
    for (int idx = t; idx < CH * KK * WT; idx += PREPT) {
      const int pp = idx & (WT - 1), rest = idx >> 5, k = rest % KK, cl = rest / KK;
      const int i0 = s_i0[k][pp], j0 = s_j0[k][pp], i1 = i0 + 1, j1 = j0 + 1;
      const float fi = s_fi[k][pp], fj = s_fj[k][pp];
      const float* xb = x + (size_t)(b * C + c0 + cl) * H * W;
      const float v00 = ((unsigned)i0 < (unsigned)H && (unsigned)j0 < (unsigned)W) ? xb[i0 * W + j0] : 0.f;
      const float v01 = ((unsigned)i0 < (unsigned)H && (unsigned)j1 < (unsigned)W) ? xb[i0 * W + j1] : 0.f;
      const float v10 = ((unsigned)i1 < (unsigned)H && (unsigned)j0 < (unsigned)W) ? xb[i1 * W + j0] : 0.f;
      const float v11 = ((unsigned)i1 < (unsigned)H && (unsigned)j1 < (unsigned)W) ? xb[i1 * W + j1] : 0.f;
      const float top = v00 + fj * (v01 - v00), bot = v10 + fj * (v11 - v10);
      s_m[cl * KK + k][pp] = top + fi * (bot - top);
    }
    __syncthreads();
#pragma unroll 4
    for (int k = 0; k < KC; ++k) {
      const float a = s_m[k][p];
      const float4 wv0 = *reinterpret_cast<const float4*>(&s_w[k][ob]);
      const float4 wv1 = *reinterpret_cast<const float4*>(&s_w[k][ob + 4]);
      acc[0] += a * wv0.x; acc[1] += a * wv0.y; acc[2] += a * wv0.z; acc[3] += a * wv0.w;
      acc[4] += a * wv1.x; acc[5] += a * wv1.y; acc[6] += a * wv1.z; acc[7] += a * wv1.w;
    }
  }
#pragma unroll
  for (int i = 0; i < 8; ++i)
    out[(((size_t)b * O + ob + i) * H + h) * W + w0 + p] = acc[i];
}

extern "C" void kernel_launch(void* const* d_in, const int* in_sizes, int n_in,
                              void* d_out, int out_size, void* d_ws, size_t ws_size,
                              hipStream_t stream) {
  const float* x    = (const float*)d_in[0];
  const float* offs = (const float*)d_in[1];
  const float* wgt  = (const float*)d_in[2];
  float* out = (float*)d_out;

  if (ws_size < WS_NEED) {   // fallback: round-1 kernel
    deform_conv_fused<<<B * H * (W / 32), PREPT, 0, stream>>>(x, offs, wgt, out);
    return;
  }
  char* xt = (char*)d_ws;
  unsigned short* wf = (unsigned short*)(xt + XT_BYTES);

  prep_fused<<<B * H * 2, PREPT, 0, stream>>>(x, wgt, (unsigned*)xt, wf);
  deform_mfma<<<B * H * 2, 256, 0, stream>>>(offs, xt, (const char*)wf, out);
}

// Round 13
// 30.307 us; speedup vs baseline: 1.6608x; 1.6553x over previous
//
#include <hip/hip_runtime.h>

namespace {
constexpr int B = 4, C = 64, H = 128, W = 128, O = 64, KK = 9;
constexpr int PREPT = 256;
constexpr int MAINT = 512;                                      // 8 waves/block
constexpr int WF_ELEMS = KK * 2 * 4 * 64 * 8;                   // 36864
constexpr size_t XT_BYTES = (size_t)B * H * W * C * 2;          // 16,777,216 (f16)
constexpr size_t WF_BYTES = (size_t)WF_ELEMS * 2;               // 73,728 (8KB per tap)
constexpr size_t WS_NEED  = XT_BYTES + WF_BYTES;
}

typedef float    f32x4 __attribute__((ext_vector_type(4)));
typedef _Float16 f16x2 __attribute__((ext_vector_type(2)));
typedef _Float16 f16x8 __attribute__((ext_vector_type(8)));

__device__ __forceinline__ unsigned hpack2(float a, float b) {  // 2x f32 -> packed f16
  f16x2 v; v[0] = (_Float16)a; v[1] = (_Float16)b;
  return __builtin_bit_cast(unsigned, v);
}
__device__ __forceinline__ void gload16(const void* g, void* l) {
  __builtin_amdgcn_global_load_lds(
      (const __attribute__((address_space(1))) unsigned*)g,
      (__attribute__((address_space(3))) unsigned*)l, 16, 0, 0);
}

// ---------- prep: x[b][c][h][w] f32 -> x_t[b][h][w][c] f16,  + weight->f16 frag ----------
__global__ __launch_bounds__(PREPT)
void prep_fused(const float* __restrict__ x, const float* __restrict__ wgt,
                unsigned* __restrict__ xt_u32, unsigned short* __restrict__ wf) {
  __shared__ float st[64][65];
  const int t = threadIdx.x;

  // weight -> f16 A-fragment order: o = mt*16 + (lane&15), c = ks*32 + (lane>>4)*8 + e
  const int gid = blockIdx.x * PREPT + t;
  if (gid < WF_ELEMS) {
    const int e = gid & 7, lane = (gid >> 3) & 63, mt = (gid >> 9) & 3;
    const int ks = (gid >> 11) & 1, tap = gid >> 12;
    const int o = mt * 16 + (lane & 15);
    const int c = ks * 32 + ((lane >> 4) << 3) + e;
    const _Float16 hv = (_Float16)wgt[(size_t)o * (C * KK) + c * KK + tap];
    wf[gid] = __builtin_bit_cast(unsigned short, hv);
  }

  const int half = blockIdx.x & 1, h = (blockIdx.x >> 1) & 127, b = blockIdx.x >> 8;
  const int w0 = half * 64;
#pragma unroll
  for (int it = 0; it < 16; ++it) {
    const int w = t & 63, c = it * 4 + (t >> 6);
    st[w][c] = x[((size_t)(b * C + c) * H + h) * W + w0 + w];
  }
  __syncthreads();
#pragma unroll
  for (int it = 0; it < 8; ++it) {
    const int idx = it * PREPT + t;
    const int w = idx >> 5, c2 = (idx & 31) * 2;
    xt_u32[(size_t)(((b * H + h) * W) + w0 + w) * 32 + (c2 >> 1)] = hpack2(st[w][c2], st[w][c2 + 1]);
  }
}

// ---------- main: round-9 structure, 8-wave blocks (one image row / block) ----------
__global__ __launch_bounds__(MAINT) __attribute__((amdgpu_waves_per_eu(4)))
void deform_mfma(const float* __restrict__ offs, const char* __restrict__ xt,
                 const char* __restrict__ wfg, float* __restrict__ out) {
  __shared__ unsigned short s_wf[2][4096];     // 16 KB: dbuf of one tap's A-fragments
  __shared__ unsigned short s_m[128 * 64];     // 16 KB: [block px][c] f16, swizzled
  __shared__ unsigned s_pw[8][KK][16][2];      // 9 KB:  f16x2 pairs (w00,w01),(w10,w11)
  __shared__ unsigned s_pa[8][KK][16][4];      // 18 KB: 4 corner byte-addrs

  const int t = threadIdx.x, l = t & 63, wid = t >> 6;           // wid 0..7
  const int nid = (blockIdx.x & 7) * 64 + (blockIdx.x >> 3);     // bijective XCD swizzle (512)
  const int h = nid & 127, b = nid >> 7;
  const int wbase = wid * 16;                   // wave's first pixel (global w)

  // --- sampling params: wave's 16 px x 9 taps ---
#pragma unroll
  for (int it = 0; it < 3; ++it) {
    const int item = it * 64 + l;
    if (item < KK * 16) {
      const int tap = item >> 4, pix = item & 15;
      const int ki = tap / 3, kj = tap - ki * 3;
      const int w = wbase + pix;
      const float* ob = offs + ((size_t)b * (2 * KK) + 2 * tap) * (H * W) + h * W + w;
      const float oi = ob[0], oj = ob[H * W];
      const float ci = oi + (float)(h + ki - 1);
      const float cj = oj + (float)(w + kj - 1);
      const float fli = floorf(ci), flj = floorf(cj);
      const int i0 = (int)fli, j0 = (int)flj, i1 = i0 + 1, j1 = j0 + 1;
      const float fi = ci - fli, fj = cj - flj, gi = 1.f - fi, gj = 1.f - fj;
      const bool bi0 = (unsigned)i0 < (unsigned)H, bi1 = (unsigned)i1 < (unsigned)H;
      const bool bj0 = (unsigned)j0 < (unsigned)W, bj1 = (unsigned)j1 < (unsigned)W;
      const int ic0 = min(max(i0, 0), H - 1), ic1 = min(max(i1, 0), H - 1);
      const int jc0 = min(max(j0, 0), W - 1), jc1 = min(max(j1, 0), W - 1);
      const float w00 = gi * gj * (float)(bi0 && bj0);
      const float w01 = gi * fj * (float)(bi0 && bj1);
      const float w10 = fi * gj * (float)(bi1 && bj0);
      const float w11 = fi * fj * (float)(bi1 && bj1);
      s_pw[wid][tap][pix][0] = hpack2(w00, w01);
      s_pw[wid][tap][pix][1] = hpack2(w10, w11);
      s_pa[wid][tap][pix][0] = (unsigned)(((b * H + ic0) * W + jc0) << 7);
      s_pa[wid][tap][pix][1] = (unsigned)(((b * H + ic0) * W + jc1) << 7);
      s_pa[wid][tap][pix][2] = (unsigned)(((b * H + ic1) * W + jc0) << 7);
      s_pa[wid][tap][pix][3] = (unsigned)(((b * H + ic1) * W + jc1) << 7);
    }
  }

  // gather lane map: 8 lanes (oct) cover one pixel-corner's 128B contiguously
  const int pix8 = l >> 3, oct = l & 7, cb = oct << 4;

  char* smb = (char*)s_m;
  const int wb  = ((wid * 16 + pix8) << 7) + ((oct ^ pix8) << 4);  // stage hs -> +hs*1024
  const int rr  = wid * 16 + (l & 15);
  const int rd0 = (rr << 7) + ((((l >> 4)    ) ^ (l & 7)) << 4);
  const int rd1 = (rr << 7) + (((4 + (l >> 4)) ^ (l & 7)) << 4);

  f32x4 acc[4];
#pragma unroll
  for (int mt = 0; mt < 4; ++mt) acc[mt] = (f32x4)0.f;

  uint4 g[2][4];   // 2-stage ring: stage hs covers px hs*8..hs*8+7, 4 corners
#define ISSUE(TAPX, HS) do {                                                   \
    const uint4 ad = *(const uint4*)&s_pa[wid][(TAPX)][(HS) * 8 + pix8][0];    \
    g[HS][0] = *(const uint4*)(xt + ad.x + cb);                                \
    g[HS][1] = *(const uint4*)(xt + ad.y + cb);                                \
    g[HS][2] = *(const uint4*)(xt + ad.z + cb);                                \
    g[HS][3] = *(const uint4*)(xt + ad.w + cb);                                \
  } while (0)

  // packed-f16 lerp: each 32-bit word = 2 channels; 4 pk-ops per word
#define LERPH(c0_, c1_, c2_, c3_) __builtin_bit_cast(unsigned, (f16x2)(        \
    __builtin_bit_cast(f16x2, c0_) * W00 + __builtin_bit_cast(f16x2, c1_) * W01 + \
    __builtin_bit_cast(f16x2, c2_) * W10 + __builtin_bit_cast(f16x2, c3_) * W11))

#define STAGE(TAPV, HS) do {                                                   \
    const uint2 pk = *(const uint2*)&s_pw[wid][(TAPV)][(HS) * 8 + pix8][0];    \
    const f16x2 pa_ = __builtin_bit_cast(f16x2, pk.x);                         \
    const f16x2 pb_ = __builtin_bit_cast(f16x2, pk.y);                         \
    const f16x2 W00 = {pa_[0], pa_[0]}, W01 = {pa_[1], pa_[1]};                \
    const f16x2 W10 = {pb_[0], pb_[0]}, W11 = {pb_[1], pb_[1]};                \
    uint4* gc = g[HS];                                                         \
    uint4 r;                                                                   \
    r.x = LERPH(gc[0].x, gc[1].x, gc[2].x, gc[3].x);                           \
    r.y = LERPH(gc[0].y, gc[1].y, gc[2].y, gc[3].y);                           \
    r.z = LERPH(gc[0].z, gc[1].z, gc[2].z, gc[3].z);                           \
    r.w = LERPH(gc[0].w, gc[1].w, gc[2].w, gc[3].w);                           \
    *(uint4*)(smb + wb + (HS) * 1024) = r;                                     \
  } while (0)

  // prologue: stage tap 0's weights into buf 0 (512 thr x 16B = 8KB, one instr)
  gload16(wfg + (size_t)t * 16, (char*)s_wf + t * 16);
  ISSUE(0, 0);
  ISSUE(0, 1);

#pragma unroll 1
  for (int tap = 0; tap < KK; ++tap) {
    __syncthreads();   // wf buf[tap&1] ready; prev-buf reads done

    if (tap + 1 < KK) {            // stage next tap's weights into the other buffer
      gload16(wfg + (size_t)(tap + 1) * 8192 + t * 16,
              (char*)s_wf + ((tap + 1) & 1) * 8192 + t * 16);
    }

    STAGE(tap, 0);
    if (tap + 1 < KK) ISSUE(tap + 1, 0);
    STAGE(tap, 1);
    if (tap + 1 < KK) ISSUE(tap + 1, 1);

    const char* wl = (const char*)s_wf + (tap & 1) * 8192;
    const f16x8 b0 = *(const f16x8*)(smb + rd0);
    const f16x8 b1 = *(const f16x8*)(smb + rd1);
#pragma unroll
    for (int mt = 0; mt < 4; ++mt) {
      const f16x8 a0 = *(const f16x8*)(wl + mt * 1024 + l * 16);
      acc[mt] = __builtin_amdgcn_mfma_f32_16x16x32_f16(a0, b0, acc[mt], 0, 0, 0);
    }
#pragma unroll
    for (int mt = 0; mt < 4; ++mt) {
      const f16x8 a1 = *(const f16x8*)(wl + 4096 + mt * 1024 + l * 16);
      acc[mt] = __builtin_amdgcn_mfma_f32_16x16x32_f16(a1, b1, acc[mt], 0, 0, 0);
    }
  }
#undef ISSUE
#undef LERPH
#undef STAGE

  // --- epilogue: coalesced stores (D: col=lane&15 -> pixel, row=(lane>>4)*4+j -> o) ---
#pragma unroll
  for (int mt = 0; mt < 4; ++mt)
#pragma unroll
    for (int j = 0; j < 4; ++j) {
      const int o = mt * 16 + ((l >> 4) << 2) + j;
      out[((size_t)(b * O + o) * H + h) * W + wbase + (l & 15)] = acc[mt][j];
    }
}

// ---------- fallback (round-1 kernel, used only if ws too small) ----------
namespace fb {
constexpr int WT = 32, CH = 16, NCHUNK = 4, KC = 144, WPAD = 68;
}
__global__ __launch_bounds__(PREPT, 2)
void deform_conv_fused(const float* __restrict__ x, const float* __restrict__ offs,
                       const float* __restrict__ wgt, float* __restrict__ out) {
  using namespace fb;
  __shared__ int   s_i0[KK][WT];
  __shared__ int   s_j0[KK][WT];
  __shared__ float s_fi[KK][WT];
  __shared__ float s_fj[KK][WT];
  __shared__ float s_w[KC][WPAD];
  __shared__ float s_m[KC][WT + 1];
  const int t = threadIdx.x;
  const int nwt = W / WT;
  const int wt = blockIdx.x % nwt, h = (blockIdx.x / nwt) % H, b = blockIdx.x / (nwt * H);
  const int w0 = wt * WT;
  for (int idx = t; idx < KK * WT; idx += PREPT) {
    const int k = idx / WT, p = idx % WT, w = w0 + p;
    const float oi = offs[(((size_t)b * (2 * KK) + 2 * k) * H + h) * W + w];
    const float oj = offs[(((size_t)b * (2 * KK) + 2 * k + 1) * H + h) * W + w];
    const float ci = oi + (float)(h + (k / 3) - 1), cj = oj + (float)(w + (k % 3) - 1);
    const float fli = floorf(ci), flj = floorf(cj);
    s_i0[k][p] = (int)fli; s_j0[k][p] = (int)flj;
    s_fi[k][p] = ci - fli; s_fj[k][p] = cj - flj;
  }
  float acc[8];
#pragma unroll
  for (int i = 0; i < 8; ++i) acc[i] = 0.f;
  const int p = t & (WT - 1), ob = (t >> 5) * 8;
  for (int cc = 0; cc < NCHUNK; ++cc) {
    const int c0 = cc * CH;
    __syncthreads();
    for (int idx = t; idx < O * KC; idx += PREPT)
      s_w[idx % KC][idx / KC] = wgt[(size_t)(idx / KC) * (C * KK) + (size_t)c0 * KK + idx % KC];
    for (int idx = t; idx < CH * KK * WT; idx += PREPT) {
      const int pp = idx & (WT - 1), rest = idx >> 5, k = rest % KK, cl = rest / KK;
      const int i0 = s_i0[k][pp], j0 = s_j0[k][pp], i1 = i0 + 1, j1 = j0 + 1;
      const float fi = s_fi[k][pp], fj = s_fj[k][pp];
      const float* xb = x + (size_t)(b * C + c0 + cl) * H * W;
      const float v00 = ((unsigned)i0 < (unsigned)H && (unsigned)j0 < (unsigned)W) ? xb[i0 * W + j0] : 0.f;
      const float v01 = ((unsigned)i0 < (unsigned)H && (unsigned)j1 < (unsigned)W) ? xb[i0 * W + j1] : 0.f;
      const float v10 = ((unsigned)i1 < (unsigned)H && (unsigned)j0 < (unsigned)W) ? xb[i1 * W + j0] : 0.f;
      const float v11 = ((unsigned)i1 < (unsigned)H && (unsigned)j1 < (unsigned)W) ? xb[i1 * W + j1] : 0.f;
      const float top = v00 + fj * (v01 - v00), bot = v10 + fj * (v11 - v10);
      s_m[cl * KK + k][pp] = top + fi * (bot - top);
    }
    __syncthreads();
#pragma unroll 4
    for (int k = 0; k < KC; ++k) {
      const float a = s_m[k][p];
      const float4 wv0 = *reinterpret_cast<const float4*>(&s_w[k][ob]);
      const float4 wv1 = *reinterpret_cast<const float4*>(&s_w[k][ob + 4]);
      acc[0] += a * wv0.x; acc[1] += a * wv0.y; acc[2] += a * wv0.z; acc[3] += a * wv0.w;
      acc[4] += a * wv1.x; acc[5] += a * wv1.y; acc[6] += a * wv1.z; acc[7] += a * wv1.w;
    }
  }
#pragma unroll
  for (int i = 0; i < 8; ++i)
    out[(((size_t)b * O + ob + i) * H + h) * W + w0 + p] = acc[i];
}

extern "C" void kernel_launch(void* const* d_in, const int* in_sizes, int n_in,
                              void* d_out, int out_size, void* d_ws, size_t ws_size,
                              hipStream_t stream) {
  const float* x    = (const float*)d_in[0];
  const float* offs = (const float*)d_in[1];
  const float* wgt  = (const float*)d_in[2];
  float* out = (float*)d_out;

  if (ws_size < WS_NEED) {   // fallback: round-1 kernel
    deform_conv_fused<<<B * H * (W / 32), PREPT, 0, stream>>>(x, offs, wgt, out);
    return;
  }
  char* xt = (char*)d_ws;
  unsigned short* wf = (unsigned short*)(xt + XT_BYTES);

  prep_fused<<<B * H * 2, PREPT, 0, stream>>>(x, wgt, (unsigned*)xt, wf);
  deform_mfma<<<B * H, MAINT, 0, stream>>>(offs, xt, (const char*)wf, out);
}

// Round 14
// 29.729 us; speedup vs baseline: 1.6931x; 1.0195x over previous
//
#include <hip/hip_runtime.h>

namespace {
constexpr int B = 4, C = 64, H = 128, W = 128, O = 64, KK = 9;
constexpr int PREPT = 256;
constexpr int MAINT = 512;                                      // 8 waves/block
constexpr int WF_ELEMS = KK * 2 * 4 * 64 * 8;                   // 36864
constexpr size_t XT_BYTES = (size_t)B * H * W * C * 2;          // 8,388,608 (f16)
constexpr size_t WF_BYTES = (size_t)WF_ELEMS * 2;               // 73,728 (8KB per tap)
constexpr size_t WS_NEED  = XT_BYTES + WF_BYTES;
}

typedef float    f32x4 __attribute__((ext_vector_type(4)));
typedef _Float16 f16x2 __attribute__((ext_vector_type(2)));
typedef _Float16 f16x8 __attribute__((ext_vector_type(8)));

__device__ __forceinline__ unsigned hpack2(float a, float b) {  // 2x f32 -> packed f16
  f16x2 v; v[0] = (_Float16)a; v[1] = (_Float16)b;
  return __builtin_bit_cast(unsigned, v);
}
__device__ __forceinline__ void gload16(const void* g, void* l) {
  __builtin_amdgcn_global_load_lds(
      (const __attribute__((address_space(1))) unsigned*)g,
      (__attribute__((address_space(3))) unsigned*)l, 16, 0, 0);
}

// ---------- prep: x[b][c][h][w] f32 -> x_t[b][h][w][c] f16,  + weight->f16 frag ----------
__global__ __launch_bounds__(PREPT)
void prep_fused(const float* __restrict__ x, const float* __restrict__ wgt,
                unsigned* __restrict__ xt_u32, unsigned short* __restrict__ wf) {
  __shared__ float st[64][65];
  const int t = threadIdx.x;

  // weight -> f16 A-fragment order: o = mt*16 + (lane&15), c = ks*32 + (lane>>4)*8 + e
  const int gid = blockIdx.x * PREPT + t;
  if (gid < WF_ELEMS) {
    const int e = gid & 7, lane = (gid >> 3) & 63, mt = (gid >> 9) & 3;
    const int ks = (gid >> 11) & 1, tap = gid >> 12;
    const int o = mt * 16 + (lane & 15);
    const int c = ks * 32 + ((lane >> 4) << 3) + e;
    const _Float16 hv = (_Float16)wgt[(size_t)o * (C * KK) + c * KK + tap];
    wf[gid] = __builtin_bit_cast(unsigned short, hv);
  }

  const int half = blockIdx.x & 1, h = (blockIdx.x >> 1) & 127, b = blockIdx.x >> 8;
  const int w0 = half * 64;
#pragma unroll
  for (int it = 0; it < 16; ++it) {
    const int w = t & 63, c = it * 4 + (t >> 6);
    st[w][c] = x[((size_t)(b * C + c) * H + h) * W + w0 + w];
  }
  __syncthreads();
#pragma unroll
  for (int it = 0; it < 8; ++it) {
    const int idx = it * PREPT + t;
    const int w = idx >> 5, c2 = (idx & 31) * 2;
    xt_u32[(size_t)(((b * H + h) * W) + w0 + w) * 32 + (c2 >> 1)] = hpack2(st[w][c2], st[w][c2 + 1]);
  }
}

// ---------- main: 8-wave blocks, 2-tap weight dbuf (barrier per 2 taps) ----------
__global__ __launch_bounds__(MAINT) __attribute__((amdgpu_waves_per_eu(4)))
void deform_mfma(const float* __restrict__ offs, const char* __restrict__ xt,
                 const char* __restrict__ wfg, float* __restrict__ out) {
  __shared__ unsigned short s_wf[4][4096];     // 32 KB: 2 buffers x 2 taps x 8KB
  __shared__ unsigned short s_m[128 * 64];     // 16 KB: [block px][c] f16, swizzled
  __shared__ unsigned s_pw[8][KK][16][2];      // 9 KB:  f16x2 pairs (w00,w01),(w10,w11)
  __shared__ unsigned s_pp[8][KK][16];         // 4.5 KB: packed jc0|ic0<<7|jc1<<14|ic1<<21

  const int t = threadIdx.x, l = t & 63, wid = t >> 6;           // wid 0..7
  const int nid = (blockIdx.x & 7) * 64 + (blockIdx.x >> 3);     // bijective XCD swizzle (512)
  const int h = nid & 127, b = nid >> 7;
  const int wbase = wid * 16;                   // wave's first pixel (global w)

  // --- sampling params: wave's 16 px x 9 taps ---
#pragma unroll
  for (int it = 0; it < 3; ++it) {
    const int item = it * 64 + l;
    if (item < KK * 16) {
      const int tap = item >> 4, pix = item & 15;
      const int ki = tap / 3, kj = tap - ki * 3;
      const int w = wbase + pix;
      const float* ob = offs + ((size_t)b * (2 * KK) + 2 * tap) * (H * W) + h * W + w;
      const float oi = ob[0], oj = ob[H * W];
      const float ci = oi + (float)(h + ki - 1);
      const float cj = oj + (float)(w + kj - 1);
      const float fli = floorf(ci), flj = floorf(cj);
      const int i0 = (int)fli, j0 = (int)flj, i1 = i0 + 1, j1 = j0 + 1;
      const float fi = ci - fli, fj = cj - flj, gi = 1.f - fi, gj = 1.f - fj;
      const bool bi0 = (unsigned)i0 < (unsigned)H, bi1 = (unsigned)i1 < (unsigned)H;
      const bool bj0 = (unsigned)j0 < (unsigned)W, bj1 = (unsigned)j1 < (unsigned)W;
      const int ic0 = min(max(i0, 0), H - 1), ic1 = min(max(i1, 0), H - 1);
      const int jc0 = min(max(j0, 0), W - 1), jc1 = min(max(j1, 0), W - 1);
      const float w00 = gi * gj * (float)(bi0 && bj0);
      const float w01 = gi * fj * (float)(bi0 && bj1);
      const float w10 = fi * gj * (float)(bi1 && bj0);
      const float w11 = fi * fj * (float)(bi1 && bj1);
      s_pw[wid][tap][pix][0] = hpack2(w00, w01);
      s_pw[wid][tap][pix][1] = hpack2(w10, w11);
      s_pp[wid][tap][pix] = (unsigned)jc0 | ((unsigned)ic0 << 7) |
                            ((unsigned)jc1 << 14) | ((unsigned)ic1 << 21);
    }
  }

  // gather lane map: 8 lanes (oct) cover one pixel-corner's 128B contiguously
  const int pix8 = l >> 3, oct = l & 7, cb = oct << 4;
  const char* xb = xt + ((size_t)b * H * W << 7) + cb;   // per-image base + lane chunk

  char* smb = (char*)s_m;
  char* smw = (char*)s_wf;
  const int wb  = ((wid * 16 + pix8) << 7) + ((oct ^ pix8) << 4);  // stage hs -> +hs*1024
  const int rr  = wid * 16 + (l & 15);
  const int rd0 = (rr << 7) + ((((l >> 4)    ) ^ (l & 7)) << 4);
  const int rd1 = (rr << 7) + (((4 + (l >> 4)) ^ (l & 7)) << 4);

  f32x4 acc[4];
#pragma unroll
  for (int mt = 0; mt < 4; ++mt) acc[mt] = (f32x4)0.f;

  uint4 g[2][4];   // 2-stage ring: stage hs covers px hs*8..hs*8+7, 4 corners
#define ISSUE(TAPX, HS) do {                                                   \
    const unsigned v_ = s_pp[wid][(TAPX)][(HS) * 8 + pix8];                    \
    const unsigned i0s = v_ & 0x3F80u;                                         \
    const unsigned j0_ = v_ & 0x7Fu;                                           \
    const unsigned j1_ = (v_ >> 14) & 0x7Fu;                                   \
    const unsigned i1s = (v_ >> 14) & 0x3F80u;                                 \
    g[HS][0] = *(const uint4*)(xb + ((size_t)(i0s | j0_) << 7));               \
    g[HS][1] = *(const uint4*)(xb + ((size_t)(i0s | j1_) << 7));               \
    g[HS][2] = *(const uint4*)(xb + ((size_t)(i1s | j0_) << 7));               \
    g[HS][3] = *(const uint4*)(xb + ((size_t)(i1s | j1_) << 7));               \
  } while (0)

  // packed-f16 lerp: each 32-bit word = 2 channels; 4 pk-ops per word
#define LERPH(c0_, c1_, c2_, c3_) __builtin_bit_cast(unsigned, (f16x2)(        \
    __builtin_bit_cast(f16x2, c0_) * W00 + __builtin_bit_cast(f16x2, c1_) * W01 + \
    __builtin_bit_cast(f16x2, c2_) * W10 + __builtin_bit_cast(f16x2, c3_) * W11))

#define STAGE(TAPV, HS) do {                                                   \
    const uint2 pk = *(const uint2*)&s_pw[wid][(TAPV)][(HS) * 8 + pix8][0];    \
    const f16x2 pa_ = __builtin_bit_cast(f16x2, pk.x);                         \
    const f16x2 pb_ = __builtin_bit_cast(f16x2, pk.y);                         \
    const f16x2 W00 = {pa_[0], pa_[0]}, W01 = {pa_[1], pa_[1]};                \
    const f16x2 W10 = {pb_[0], pb_[0]}, W11 = {pb_[1], pb_[1]};                \
    uint4* gc = g[HS];                                                         \
    uint4 r;                                                                   \
    r.x = LERPH(gc[0].x, gc[1].x, gc[2].x, gc[3].x);                           \
    r.y = LERPH(gc[0].y, gc[1].y, gc[2].y, gc[3].y);                           \
    r.z = LERPH(gc[0].z, gc[1].z, gc[2].z, gc[3].z);                           \
    r.w = LERPH(gc[0].w, gc[1].w, gc[2].w, gc[3].w);                           \
    *(uint4*)(smb + wb + (HS) * 1024) = r;                                     \
  } while (0)

#define DO_TAP(TAPV, WL) do {                                                  \
    STAGE(TAPV, 0);                                                            \
    if ((TAPV) + 1 < KK) ISSUE((TAPV) + 1, 0);                                 \
    STAGE(TAPV, 1);                                                            \
    if ((TAPV) + 1 < KK) ISSUE((TAPV) + 1, 1);                                 \
    const f16x8 b0 = *(const f16x8*)(smb + rd0);                               \
    const f16x8 b1 = *(const f16x8*)(smb + rd1);                               \
    __builtin_amdgcn_s_setprio(1);                                             \
    _Pragma("unroll")                                                          \
    for (int mt = 0; mt < 4; ++mt) {                                           \
      const f16x8 a0 = *(const f16x8*)((WL) + mt * 1024 + l * 16);             \
      acc[mt] = __builtin_amdgcn_mfma_f32_16x16x32_f16(a0, b0, acc[mt], 0, 0, 0); \
    }                                                                          \
    _Pragma("unroll")                                                          \
    for (int mt = 0; mt < 4; ++mt) {                                           \
      const f16x8 a1 = *(const f16x8*)((WL) + 4096 + mt * 1024 + l * 16);      \
      acc[mt] = __builtin_amdgcn_mfma_f32_16x16x32_f16(a1, b1, acc[mt], 0, 0, 0); \
    }                                                                          \
    __builtin_amdgcn_s_setprio(0);                                             \
  } while (0)

  // prologue: stage taps 0,1 into buffer 0; prefetch tap 0's gathers
  gload16(wfg + (size_t)t * 16, smw + t * 16);
  gload16(wfg + 8192 + (size_t)t * 16, smw + 8192 + t * 16);
  ISSUE(0, 0);
  ISSUE(0, 1);

#pragma unroll 1
  for (int pair = 0; pair < 5; ++pair) {      // taps {2p, 2p+1}; pair 4 = tap 8 only
    const int t0 = pair * 2;
    __syncthreads();   // buffer (pair&1) ready; prev-buffer A-reads drained

    if (pair < 4) {                            // stage next pair's weights
      const int n0 = t0 + 2;
      char* dst = smw + ((pair + 1) & 1) * 16384;
      gload16(wfg + (size_t)n0 * 8192 + t * 16, dst + t * 16);
      if (n0 + 1 < KK)
        gload16(wfg + (size_t)(n0 + 1) * 8192 + t * 16, dst + 8192 + t * 16);
    }

    const char* wl0 = smw + (pair & 1) * 16384;
    DO_TAP(t0, wl0);
    if (t0 + 1 < KK) DO_TAP(t0 + 1, wl0 + 8192);
  }
#undef ISSUE
#undef LERPH
#undef STAGE
#undef DO_TAP

  // --- epilogue: coalesced stores (D: col=lane&15 -> pixel, row=(lane>>4)*4+j -> o) ---
#pragma unroll
  for (int mt = 0; mt < 4; ++mt)
#pragma unroll
    for (int j = 0; j < 4; ++j) {
      const int o = mt * 16 + ((l >> 4) << 2) + j;
      out[((size_t)(b * O + o) * H + h) * W + wbase + (l & 15)] = acc[mt][j];
    }
}

// ---------- fallback (round-1 kernel, used only if ws too small) ----------
namespace fb {
constexpr int WT = 32, CH = 16, NCHUNK = 4, KC = 144, WPAD = 68;
}
__global__ __launch_bounds__(PREPT, 2)
void deform_conv_fused(const float* __restrict__ x, const float* __restrict__ offs,
                       const float* __restrict__ wgt, float* __restrict__ out) {
  using namespace fb;
  __shared__ int   s_i0[KK][WT];
  __shared__ int   s_j0[KK][WT];
  __shared__ float s_fi[KK][WT];
  __shared__ float s_fj[KK][WT];
  __shared__ float s_w[KC][WPAD];
  __shared__ float s_m[KC][WT + 1];
  const int t = threadIdx.x;
  const int nwt = W / WT;
  const int wt = blockIdx.x % nwt, h = (blockIdx.x / nwt) % H, b = blockIdx.x / (nwt * H);
  const int w0 = wt * WT;
  for (int idx = t; idx < KK * WT; idx += PREPT) {
    const int k = idx / WT, p = idx % WT, w = w0 + p;
    const float oi = offs[(((size_t)b * (2 * KK) + 2 * k) * H + h) * W + w];
    const float oj = offs[(((size_t)b * (2 * KK) + 2 * k + 1) * H + h) * W + w];
    const float ci = oi + (float)(h + (k / 3) - 1), cj = oj + (float)(w + (k % 3) - 1);
    const float fli = floorf(ci), flj = floorf(cj);
    s_i0[k][p] = (int)fli; s_j0[k][p] = (int)flj;
    s_fi[k][p] = ci - fli; s_fj[k][p] = cj - flj;
  }
  float acc[8];
#pragma unroll
  for (int i = 0; i < 8; ++i) acc[i] = 0.f;
  const int p = t & (WT - 1), ob = (t >> 5) * 8;
  for (int cc = 0; cc < NCHUNK; ++cc) {
    const int c0 = cc * CH;
    __syncthreads();
    for (int idx = t; idx < O * KC; idx += PREPT)
      s_w[idx % KC][idx / KC] = wgt[(size_t)(idx / KC) * (C * KK) + (size_t)c0 * KK + idx % KC];
    for (int idx = t; idx < CH * KK * WT; idx += PREPT) {
      const int pp = idx & (WT - 1), rest = idx >> 5, k = rest % KK, cl = rest / KK;
      const int i0 = s_i0[k][pp], j0 = s_j0[k][pp], i1 = i0 + 1, j1 = j0 + 1;
      const float fi = s_fi[k][pp], fj = s_fj[k][pp];
      const float* xb = x + (size_t)(b * C + c0 + cl) * H * W;
      const float v00 = ((unsigned)i0 < (unsigned)H && (unsigned)j0 < (unsigned)W) ? xb[i0 * W + j0] : 0.f;
      const float v01 = ((unsigned)i0 < (unsigned)H && (unsigned)j1 < (unsigned)W) ? xb[i0 * W + j1] : 0.f;
      const float v10 = ((unsigned)i1 < (unsigned)H && (unsigned)j0 < (unsigned)W) ? xb[i1 * W + j0] : 0.f;
      const float v11 = ((unsigned)i1 < (unsigned)H && (unsigned)j1 < (unsigned)W) ? xb[i1 * W + j1] : 0.f;
      const float top = v00 + fj * (v01 - v00), bot = v10 + fj * (v11 - v10);
      s_m[cl * KK + k][pp] = top + fi * (bot - top);
    }
    __syncthreads();
#pragma unroll 4
    for (int k = 0; k < KC; ++k) {
      const float a = s_m[k][p];
      const float4 wv0 = *reinterpret_cast<const float4*>(&s_w[k][ob]);
      const float4 wv1 = *reinterpret_cast<const float4*>(&s_w[k][ob + 4]);
      acc[0] += a * wv0.x; acc[1] += a * wv0.y; acc[2] += a * wv0.z; acc[3] += a * wv0.w;
      acc[4] += a * wv1.x; acc[5] += a * wv1.y; acc[6] += a * wv1.z; acc[7] += a * wv1.w;
    }
  }
#pragma unroll
  for (int i = 0; i < 8; ++i)
    out[(((size_t)b * O + ob + i) * H + h) * W + w0 + p] = acc[i];
}

extern "C" void kernel_launch(void* const* d_in, const int* in_sizes, int n_in,
                              void* d_out, int out_size, void* d_ws, size_t ws_size,
                              hipStream_t stream) {
  const float* x    = (const float*)d_in[0];
  const float* offs = (const float*)d_in[1];
  const float* wgt  = (const float*)d_in[2];
  float* out = (float*)d_out;

  if (ws_size < WS_NEED) {   // fallback: round-1 kernel
    deform_conv_fused<<<B * H * (W / 32), PREPT, 0, stream>>>(x, offs, wgt, out);
    return;
  }
  char* xt = (char*)d_ws;
  unsigned short* wf = (unsigned short*)(xt + XT_BYTES);

  prep_fused<<<B * H * 2, PREPT, 0, stream>>>(x, wgt, (unsigned*)xt, wf);
  deform_mfma<<<B * H, MAINT, 0, stream>>>(offs, xt, (const char*)wf, out);
}